// Round 3
// baseline (53918.726 us; speedup 1.0000x reference)
//
#include <hip/hip_runtime.h>

#define B     16
#define TENC  128
#define TDEC  100
#define IND   256
#define HID   256
#define OD    400
#define MD    80
#define LBUF  17
#define BD    336
#define BS    5712
#define BH    571
#define MH    40
#define NSLOT 117

// persistent-scan geometry
#define NWKC  16      // K chunks
#define WCH   360     // K per chunk (16*360 = 5760 >= 5712, padded)
#define NCT   13      // col tiles of 64 (832 >= 827)
#define NWORK (NWKC*NCT)   // 208 worker blocks
#define NBLK  (NWORK + B)  // + 16 consumer blocks
#define KPT   48      // k per kq-slot (8 slots * 48 = 384 padded)
#define USTR  20      // u LDS stride per k (pad for banks, 16B-aligned groups)
#define UKL   384

// workspace layout (float offsets)
#define OFF_U    0
#define OFF_PA   628992      // + 117*16*336
#define OFF_MEM  1153280     // + 16*128*256
#define OFF_M    1281280     // + 100*16*80
#define OFF_CO   3566080     // + 17*336*400
#define OFF_P    3566480     // + 400
#define OFF_Q    3992464     // + 2*16*16*832
#define OFF_FLG  6552464     // + 4*16*100*400 ; flags: 256 ints

__global__ __launch_bounds__(256) void k_init(float* __restrict__ ws) {
    int i = blockIdx.x*256 + threadIdx.x;
    int nu = 17*B*BD;                       // u_{-17..-1} = 0
    if (i < nu) ws[OFF_U + i] = 0.f;
    else if (i < nu + OD) ws[OFF_CO + (i - nu)] = 0.f;
    else if (i < nu + OD + 256) ws[OFF_FLG + (i - nu - OD)] = 0.f;  // prog/cons flags
}

// pa[b,j,h] = inputs[b,j,:] @ att_wa[:,h] + att_ba[h]
__global__ __launch_bounds__(256) void k_pa(const float* __restrict__ inputs,
        const float* __restrict__ wa, const float* __restrict__ ba,
        float* __restrict__ ws) {
    int bj = blockIdx.x;
    int tid = threadIdx.x;
    __shared__ float xin[IND];
    xin[tid] = inputs[bj*IND + tid];
    __syncthreads();
    float acc = ba[tid];
    #pragma unroll 4
    for (int i = 0; i < IND; i++) acc += xin[i]*wa[i*HID + tid];
    ws[OFF_PA + bj*HID + tid] = acc;
}

__global__ __launch_bounds__(128) void k_mem(const float* __restrict__ targets,
        const float* __restrict__ w1, const float* __restrict__ b1,
        const float* __restrict__ w2, const float* __restrict__ b2,
        float* __restrict__ ws) {
    int tb = blockIdx.x; int t = tb / B; int b = tb % B;
    int tid = threadIdx.x;
    __shared__ float xin[OD];
    __shared__ float hid[MH];
    for (int k = tid; k < OD; k += 128)
        xin[k] = (t == 0) ? 0.f : targets[(b*TDEC + (t-1))*OD + k];
    __syncthreads();
    if (tid < MH) {
        float a = b1[tid];
        for (int k = 0; k < OD; k++) a += xin[k]*w1[k*MH + tid];
        hid[tid] = fmaxf(a, 0.f);
    }
    __syncthreads();
    if (tid < MD) {
        float a = b2[tid];
        #pragma unroll
        for (int k = 0; k < MH; k++) a += hid[k]*w2[k*MD + tid];
        ws[OFF_MEM + (t*B + b)*MD + tid] = a;
    }
}

// M[l][d][o] = sum_h scale_w[h][d] * out_w[l*256+h][o]
__global__ __launch_bounds__(256) void k_M(const float* __restrict__ scale_w,
        const float* __restrict__ out_w, float* __restrict__ ws) {
    int l  = blockIdx.x / 14;
    int d0 = (blockIdx.x % 14) * 24;
    int tid = threadIdx.x;
    __shared__ float sw[HID*24];
    for (int idx = tid; idx < HID*24; idx += 256) {
        int h = idx / 24, dl = idx % 24;
        sw[idx] = scale_w[h*BD + d0 + dl];
    }
    __syncthreads();
    int o0 = tid, o1 = tid + 256;
    bool v1 = o1 < OD;
    float a0[24], a1[24];
    #pragma unroll
    for (int i = 0; i < 24; i++) { a0[i] = 0.f; a1[i] = 0.f; }
    const float* owl = out_w + l*HID*OD;
    for (int h = 0; h < HID; h++) {
        float w0 = owl[h*OD + o0];
        float w1v = v1 ? owl[h*OD + o1] : 0.f;
        #pragma unroll
        for (int dl = 0; dl < 24; dl++) {
            float s = sw[h*24 + dl];
            a0[dl] += s*w0; a1[dl] += s*w1v;
        }
    }
    float* Mp = ws + OFF_M + l*BD*OD;
    for (int dl = 0; dl < 24; dl++) {
        Mp[(d0+dl)*OD + o0] = a0[dl];
        if (v1) Mp[(d0+dl)*OD + o1] = a1[dl];
    }
}

__global__ __launch_bounds__(256) void k_cout(const float* __restrict__ scale_b,
        const float* __restrict__ out_w, const float* __restrict__ out_b,
        float* __restrict__ ws) {
    int l = blockIdx.x; int tid = threadIdx.x;
    for (int p = 0; p < 2; p++) {
        int o = tid + p*256;
        if (o < OD) {
            float acc = (l == 0) ? out_b[o] : 0.f;
            for (int h = 0; h < HID; h++) acc += scale_b[h]*out_w[(l*HID + h)*OD + o];
            atomicAdd(&ws[OFF_CO + o], acc);
        }
    }
}

// ---------------- persistent scan kernel ----------------
// blocks 0..207: workers (kc = b/13, ct = b%13). Weights in registers.
// blocks 208..223: consumers (one per batch row).
// Flags (ints, in ws): prog[0..99] at OFF_FLG, cons[0..99] at OFF_FLG+128.
__global__ __launch_bounds__(512, 2) void k_scan(
        const float* __restrict__ inputs, const float* __restrict__ wq,
        const float* __restrict__ w1g, const float* __restrict__ att_bq,
        const float* __restrict__ bp_b1, const float* __restrict__ bp_b2,
        const float* __restrict__ bp_w2, const float* __restrict__ att_v,
        float* __restrict__ ws, float* __restrict__ attns) {
    __shared__ __align__(16) char smem[63488];
    int bid = blockIdx.x, tid = threadIdx.x;
    int* prog = (int*)(ws + OFF_FLG);
    int* cons = prog + 128;

    if (bid < NWORK) {
        // ================= WORKER =================
        int kc = bid / NCT, ct = bid % NCT;
        float* ulds = (float*)smem;                 // UKL*USTR = 7680 floats
        float* red  = (float*)(smem + UKL*USTR*4);  // 8192 floats
        int cp = tid & 31, kq = (tid >> 5) & 7;
        bool comp = tid < 256;
        int g0 = ct*64 + cp, g1 = g0 + 32;
        float w0[KPT], w1r[KPT];
        #pragma unroll
        for (int g = 0; g < KPT; g++) { w0[g] = 0.f; w1r[g] = 0.f; }
        if (comp) {
            #pragma unroll
            for (int g = 0; g < KPT; g++) {
                int kl = kq*KPT + g;
                int kg = kc*WCH + kl;
                if (kl < WCH && kg < BS) {
                    int w = kg/336, d = kg - 336*w;
                    if (g0 < 256)      w0[g] = wq[((16-w)*336+d)*HID + g0];
                    else if (g0 < 827 && kg >= 336)
                                       w0[g] = w1g[((17-w)*336+d)*BH + (g0-256)];
                    if (g1 < 256)      w1r[g] = wq[((16-w)*336+d)*HID + g1];
                    else if (g1 < 827 && kg >= 336)
                                       w1r[g] = w1g[((17-w)*336+d)*BH + (g1-256)];
                }
            }
        }
        int khiv = kc*WCH + WCH - 1; if (khiv > BS-1) khiv = BS-1;
        int whi = khiv / 336;
        for (int t = 0; t < TDEC; t++) {
            int s = t + whi - 17; int s2 = t - 2;
            if (s2 > s) s = s2;
            if (tid == 0 && s >= 0) {
                while (__hip_atomic_load(&cons[s], __ATOMIC_ACQUIRE,
                                         __HIP_MEMORY_SCOPE_AGENT) < B)
                    __builtin_amdgcn_s_sleep(1);
            }
            __syncthreads();
            // stage u window slice -> LDS [kl][b], stride USTR
            for (int e = tid; e < B*UKL; e += 512) {
                int b = e / UKL, kl = e - b*UKL;
                float v = 0.f;
                int kg = kc*WCH + kl;
                if (kl < WCH && kg < BS) {
                    int w = kg/336, d = kg - 336*w;
                    v = ws[OFF_U + ((t + w)*B + b)*BD + d];
                }
                ulds[kl*USTR + b] = v;
            }
            __syncthreads();
            if (comp) {
                float a0[16], a1[16];
                #pragma unroll
                for (int i = 0; i < 16; i++) { a0[i] = 0.f; a1[i] = 0.f; }
                #pragma unroll
                for (int g = 0; g < KPT; g++) {
                    int kb = (kq*KPT + g)*USTR;
                    float uu[16];
                    *(float4*)&uu[0]  = *(const float4*)&ulds[kb];
                    *(float4*)&uu[4]  = *(const float4*)&ulds[kb+4];
                    *(float4*)&uu[8]  = *(const float4*)&ulds[kb+8];
                    *(float4*)&uu[12] = *(const float4*)&ulds[kb+12];
                    float wa = w0[g], wb = w1r[g];
                    #pragma unroll
                    for (int bb = 0; bb < 16; bb++) {
                        a0[bb] = fmaf(wa, uu[bb], a0[bb]);
                        a1[bb] = fmaf(wb, uu[bb], a1[bb]);
                    }
                }
                #pragma unroll
                for (int bb = 0; bb < 16; bb++) {
                    red[kq*1024 + bb*64 + cp]      = a0[bb];
                    red[kq*1024 + bb*64 + cp + 32] = a1[bb];
                }
            }
            __syncthreads();
            int par = t & 1;
            for (int oi = tid; oi < 1024; oi += 512) {
                float sacc = 0.f;
                #pragma unroll
                for (int q = 0; q < 8; q++) sacc += red[q*1024 + oi];
                int bb = oi >> 6, cl = oi & 63;
                ws[OFF_P + (((par*NWKC + kc)*B + bb)*832) + ct*64 + cl] = sacc;
            }
            __syncthreads();
            if (tid == 0) {
                __threadfence();
                __hip_atomic_fetch_add(&prog[t], 1, __ATOMIC_RELEASE,
                                       __HIP_MEMORY_SCOPE_AGENT);
            }
        }
    } else {
        // ================= CONSUMER =================
        int b = bid - NWORK;
        float* pqa    = (float*)smem;            // 832
        float* sc     = pqa + 832;               // 128
        float* attn_s = sc + 128;                // 128
        float* ctx2   = attn_s + 128;            // 512
        float* topv   = ctx2 + 512;              // 336
        float* h1     = topv + 336;              // 571+1
        float* avs    = h1 + 572;                // 256
        if (tid < 256) avs[tid] = att_v[tid];
        for (int t = 0; t < TDEC; t++) {
            if (tid == 0) {
                while (__hip_atomic_load(&prog[t], __ATOMIC_ACQUIRE,
                                         __HIP_MEMORY_SCOPE_AGENT) < NWORK)
                    __builtin_amdgcn_s_sleep(1);
            }
            __syncthreads();
            int par = t & 1;
            for (int col = tid; col < 827; col += 512) {
                float ssum = 0.f;
                #pragma unroll
                for (int q = 0; q < NWKC; q++)
                    ssum += ws[OFF_P + (((par*NWKC + q)*B + b)*832) + col];
                pqa[col] = ssum + (col < HID ? att_bq[col] : bp_b1[col-HID]);
            }
            __syncthreads();
            {   // scores: thread = j*4 + hq, each 64 h
                int j = tid >> 2, hq = tid & 3;
                const float* par_ = ws + OFF_PA + (b*TENC + j)*HID + hq*64;
                const float* pqh = &pqa[hq*64];
                const float* avh = &avs[hq*64];
                float a = 0.f;
                #pragma unroll 8
                for (int h = 0; h < 64; h++) {
                    float x = pqh[h] + par_[h];
                    float e = __expf(2.f*x);
                    a += avh[h]*(1.f - 2.f/(e + 1.f));
                }
                a += __shfl_xor(a, 1);
                a += __shfl_xor(a, 2);
                if (hq == 0) sc[j] = a;
            }
            __syncthreads();
            if (tid < 64) {
                float s0 = sc[2*tid], s1 = sc[2*tid+1];
                float m = fmaxf(s0, s1);
                #pragma unroll
                for (int off = 1; off < 64; off <<= 1) m = fmaxf(m, __shfl_xor(m, off));
                float e0 = __expf(s0 - m), e1 = __expf(s1 - m);
                float ssum = e0 + e1;
                #pragma unroll
                for (int off = 1; off < 64; off <<= 1) ssum += __shfl_xor(ssum, off);
                float r = 1.f/ssum;
                attn_s[2*tid] = e0*r; attn_s[2*tid+1] = e1*r;
                attns[(b*TDEC + t)*TENC + 2*tid]   = e0*r;
                attns[(b*TDEC + t)*TENC + 2*tid+1] = e1*r;
            }
            __syncthreads();
            {   // ctx: thread = (i, j-half)
                int i = tid & 255, jh = tid >> 8;
                const float* inp = inputs + (b*TENC + jh*64)*IND + i;
                float csum = 0.f;
                #pragma unroll 8
                for (int j = 0; j < 64; j++)
                    csum += attn_s[jh*64 + j]*inp[j*IND];
                ctx2[jh*256 + i] = csum;
            }
            __syncthreads();
            if (tid < 256) topv[tid] = ctx2[tid] + ctx2[256 + tid];
            else if (tid < BD) topv[tid] = ws[OFF_MEM + (t*B + b)*MD + (tid-256)];
            __syncthreads();
            for (int c = tid; c < BH; c += 512) {
                float v = pqa[HID + c];
                const float* wp = w1g + c;
                #pragma unroll 4
                for (int dd = 0; dd < BD; dd++) v = fmaf(topv[dd], wp[dd*BH], v);
                h1[c] = fmaxf(v, 0.f);
            }
            __syncthreads();
            if (tid < BD) {
                float v = bp_b2[tid];
                const float* wp = bp_w2 + tid;
                #pragma unroll 4
                for (int c = 0; c < BH; c++) v = fmaf(h1[c], wp[c*BD], v);
                ws[OFF_U + ((t + 17)*B + b)*BD + tid] = v;
            }
            __syncthreads();
            if (tid == 0) {
                __threadfence();
                __hip_atomic_fetch_add(&cons[t], 1, __ATOMIC_RELEASE,
                                       __HIP_MEMORY_SCOPE_AGENT);
            }
        }
    }
}

// Output head: Q[lc][b][t][o] = sum_{l in chunk, d} u_{t-l}[b][d]*M[l][d][o]
// grid = 16 b x 7 t-tiles(16) x 4 l-chunks
__global__ __launch_bounds__(256) void k_q2(float* __restrict__ ws) {
    int bid = blockIdx.x;
    int lc = bid & 3, tt = (bid >> 2) % 7, b = bid / 28;
    int l0 = lc*4, le = (lc == 3) ? 5 : 4;
    int t0 = tt*16;
    int ns = 15 + le;
    int s0 = t0 + 17 - (l0 + le - 1);
    __shared__ __align__(16) float Uw[20*336];
    int tid = threadIdx.x;
    for (int idx = tid; idx < ns*336; idx += 256) {
        int r = idx/336, d = idx - r*336;
        int slot = s0 + r;
        Uw[idx] = (slot >= 0 && slot < NSLOT) ? ws[OFF_U + (slot*B + b)*BD + d] : 0.f;
    }
    __syncthreads();
    int o0 = tid, o1 = tid + 256;
    bool v1 = o1 < OD;
    float a[16], c[16];
    #pragma unroll
    for (int i = 0; i < 16; i++) { a[i] = 0.f; c[i] = 0.f; }
    for (int l = l0; l < l0 + le; l++) {
        const float* Mrow = ws + OFF_M + l*BD*OD;
        const float* urow = &Uw[(l0 + le - 1 - l)*336];
        for (int dg = 0; dg < 84; dg++) {
            int d = dg*4;
            float m00 = Mrow[(d+0)*OD + o0], m01 = Mrow[(d+1)*OD + o0];
            float m02 = Mrow[(d+2)*OD + o0], m03 = Mrow[(d+3)*OD + o0];
            float m10 = 0.f, m11 = 0.f, m12 = 0.f, m13 = 0.f;
            if (v1) {
                m10 = Mrow[(d+0)*OD + o1]; m11 = Mrow[(d+1)*OD + o1];
                m12 = Mrow[(d+2)*OD + o1]; m13 = Mrow[(d+3)*OD + o1];
            }
            #pragma unroll
            for (int q = 0; q < 16; q++) {
                float4 u4 = *(const float4*)&urow[q*336 + d];
                a[q] = fmaf(u4.x, m00, a[q]); a[q] = fmaf(u4.y, m01, a[q]);
                a[q] = fmaf(u4.z, m02, a[q]); a[q] = fmaf(u4.w, m03, a[q]);
                c[q] = fmaf(u4.x, m10, c[q]); c[q] = fmaf(u4.y, m11, c[q]);
                c[q] = fmaf(u4.z, m12, c[q]); c[q] = fmaf(u4.w, m13, c[q]);
            }
        }
    }
    float* Q = ws + OFF_Q + (lc*B + b)*TDEC*OD;
    for (int q = 0; q < 16; q++) {
        int tp = t0 + q;
        if (tp < TDEC) {
            Q[tp*OD + o0] = a[q];
            if (v1) Q[tp*OD + o1] = c[q];
        }
    }
}

// outs = c_out + sum of 4 l-chunk partials
__global__ __launch_bounds__(256) void k_q3(float* __restrict__ outs,
        const float* __restrict__ ws) {
    int i = blockIdx.x*256 + threadIdx.x;
    if (i < B*TDEC*OD) {
        int o = i % OD;
        float v = ws[OFF_CO + o];
        #pragma unroll
        for (int lc = 0; lc < 4; lc++) v += ws[OFF_Q + lc*B*TDEC*OD + i];
        outs[i] = v;
    }
}

extern "C" void kernel_launch(void* const* d_in, const int* in_sizes, int n_in,
                              void* d_out, int out_size, void* d_ws, size_t ws_size,
                              hipStream_t stream) {
    const float* inputs  = (const float*)d_in[0];
    const float* targets = (const float*)d_in[1];
    const float* mp_w1   = (const float*)d_in[2];
    const float* mp_b1   = (const float*)d_in[3];
    const float* mp_w2   = (const float*)d_in[4];
    const float* mp_b2   = (const float*)d_in[5];
    const float* bp_w1   = (const float*)d_in[6];
    const float* bp_b1   = (const float*)d_in[7];
    const float* bp_w2   = (const float*)d_in[8];
    const float* bp_b2   = (const float*)d_in[9];
    const float* att_wq  = (const float*)d_in[10];
    const float* att_bq  = (const float*)d_in[11];
    const float* att_wa  = (const float*)d_in[12];
    const float* att_ba  = (const float*)d_in[13];
    const float* att_v   = (const float*)d_in[14];
    const float* scale_w = (const float*)d_in[15];
    const float* scale_b = (const float*)d_in[16];
    const float* out_w   = (const float*)d_in[17];
    const float* out_b   = (const float*)d_in[18];
    float* ws = (float*)d_ws;
    float* outs = (float*)d_out;
    float* attns = outs + B*TDEC*OD;

    k_init<<<360, 256, 0, stream>>>(ws);
    k_pa  <<<B*TENC, 256, 0, stream>>>(inputs, att_wa, att_ba, ws);
    k_mem <<<TDEC*B, 128, 0, stream>>>(targets, mp_w1, mp_b1, mp_w2, mp_b2, ws);
    k_M   <<<17*14, 256, 0, stream>>>(scale_w, out_w, ws);
    k_cout<<<17, 256, 0, stream>>>(scale_b, out_w, out_b, ws);
    k_scan<<<NBLK, 512, 0, stream>>>(inputs, att_wq, bp_w1, att_bq, bp_b1,
                                     bp_b2, bp_w2, att_v, ws, attns);
    k_q2  <<<16*7*4, 256, 0, stream>>>(ws);
    k_q3  <<<(B*TDEC*OD + 255)/256, 256, 0, stream>>>(outs, ws);
}

// Round 4
// 5705.972 us; speedup vs baseline: 9.4495x; 9.4495x over previous
//
#include <hip/hip_runtime.h>

#define B     16
#define TENC  128
#define TDEC  100
#define IND   256
#define HID   256
#define OD    400
#define MD    80
#define LBUF  17
#define BD    336
#define BS    5712
#define BH    571
#define MH    40
#define NSLOT 117

// persistent-scan geometry
#define NWKC  16
#define WCH   360
#define NCT   13
#define NWORK (NWKC*NCT)   // 208 worker blocks
#define NBLK  (NWORK + B)  // + 16 consumer blocks
#define KPT   48
#define USTR  20
#define UKL   384

// workspace layout (float offsets)
#define OFF_U    0
#define OFF_PA   628992
#define OFF_MEM  1153280
#define OFF_M    1281280
#define OFF_CO   3566080
#define OFF_P    3566480
#define OFF_Q    3992464     // epilogue Q partials; ALSO w1T/w2T during scan (time-disjoint)
#define OFF_T1   OFF_Q               // w1T[c][dd] 571*336
#define OFF_T2   (OFF_Q + 191856)    // w2T[dd][c] 336*572 (c padded)
#define OFF_FLG  6552464     // flags: 3200 ints (one per 64B line)

#define RLX __ATOMIC_RELAXED
#define AGT __HIP_MEMORY_SCOPE_AGENT

__global__ __launch_bounds__(256) void k_init(float* __restrict__ ws) {
    int i = blockIdx.x*256 + threadIdx.x;
    int nu = 17*B*BD;
    if (i < nu) ws[OFF_U + i] = 0.f;
    else if (i < nu + OD) ws[OFF_CO + (i - nu)] = 0.f;
    else if (i < nu + OD + 3200) ((int*)(ws + OFF_FLG))[i - nu - OD] = 0;
}

__global__ __launch_bounds__(256) void k_pa(const float* __restrict__ inputs,
        const float* __restrict__ wa, const float* __restrict__ ba,
        float* __restrict__ ws) {
    int bj = blockIdx.x;
    int tid = threadIdx.x;
    __shared__ float xin[IND];
    xin[tid] = inputs[bj*IND + tid];
    __syncthreads();
    float acc = ba[tid];
    #pragma unroll 4
    for (int i = 0; i < IND; i++) acc += xin[i]*wa[i*HID + tid];
    ws[OFF_PA + bj*HID + tid] = acc;
}

__global__ __launch_bounds__(128) void k_mem(const float* __restrict__ targets,
        const float* __restrict__ w1, const float* __restrict__ b1,
        const float* __restrict__ w2, const float* __restrict__ b2,
        float* __restrict__ ws) {
    int tb = blockIdx.x; int t = tb / B; int b = tb % B;
    int tid = threadIdx.x;
    __shared__ float xin[OD];
    __shared__ float hid[MH];
    for (int k = tid; k < OD; k += 128)
        xin[k] = (t == 0) ? 0.f : targets[(b*TDEC + (t-1))*OD + k];
    __syncthreads();
    if (tid < MH) {
        float a = b1[tid];
        for (int k = 0; k < OD; k++) a += xin[k]*w1[k*MH + tid];
        hid[tid] = fmaxf(a, 0.f);
    }
    __syncthreads();
    if (tid < MD) {
        float a = b2[tid];
        #pragma unroll
        for (int k = 0; k < MH; k++) a += hid[k]*w2[k*MD + tid];
        ws[OFF_MEM + (t*B + b)*MD + tid] = a;
    }
}

__global__ __launch_bounds__(256) void k_M(const float* __restrict__ scale_w,
        const float* __restrict__ out_w, float* __restrict__ ws) {
    int l  = blockIdx.x / 14;
    int d0 = (blockIdx.x % 14) * 24;
    int tid = threadIdx.x;
    __shared__ float sw[HID*24];
    for (int idx = tid; idx < HID*24; idx += 256) {
        int h = idx / 24, dl = idx % 24;
        sw[idx] = scale_w[h*BD + d0 + dl];
    }
    __syncthreads();
    int o0 = tid, o1 = tid + 256;
    bool v1 = o1 < OD;
    float a0[24], a1[24];
    #pragma unroll
    for (int i = 0; i < 24; i++) { a0[i] = 0.f; a1[i] = 0.f; }
    const float* owl = out_w + l*HID*OD;
    for (int h = 0; h < HID; h++) {
        float w0 = owl[h*OD + o0];
        float w1v = v1 ? owl[h*OD + o1] : 0.f;
        #pragma unroll
        for (int dl = 0; dl < 24; dl++) {
            float s = sw[h*24 + dl];
            a0[dl] += s*w0; a1[dl] += s*w1v;
        }
    }
    float* Mp = ws + OFF_M + l*BD*OD;
    for (int dl = 0; dl < 24; dl++) {
        Mp[(d0+dl)*OD + o0] = a0[dl];
        if (v1) Mp[(d0+dl)*OD + o1] = a1[dl];
    }
}

__global__ __launch_bounds__(256) void k_cout(const float* __restrict__ scale_b,
        const float* __restrict__ out_w, const float* __restrict__ out_b,
        float* __restrict__ ws) {
    int l = blockIdx.x; int tid = threadIdx.x;
    for (int p = 0; p < 2; p++) {
        int o = tid + p*256;
        if (o < OD) {
            float acc = (l == 0) ? out_b[o] : 0.f;
            for (int h = 0; h < HID; h++) acc += scale_b[h]*out_w[(l*HID + h)*OD + o];
            atomicAdd(&ws[OFF_CO + o], acc);
        }
    }
}

// transposes for the consumer GEMVs: w1T[c][dd] = bp_w1[dd][c] (dd<336),
// w2T[dd][c] = bp_w2[c][dd] with c padded to 572 (zeros).
__global__ __launch_bounds__(256) void k_tr(const float* __restrict__ bp_w1,
        const float* __restrict__ bp_w2, float* __restrict__ ws) {
    int i = blockIdx.x*256 + threadIdx.x;
    if (i < BH*336) {
        int c = i / 336, dd = i - c*336;
        ws[OFF_T1 + c*336 + dd] = bp_w1[dd*BH + c];
    } else {
        int j = i - BH*336;
        if (j < 336*572) {
            int dd = j / 572, c = j - dd*572;
            ws[OFF_T2 + dd*572 + c] = (c < BH) ? bp_w2[c*BD + dd] : 0.f;
        }
    }
}

// ---------------- persistent scan kernel ----------------
// All cross-block data via relaxed agent-scope atomics (sc0/sc1 point-of-
// coherency ops) — NO acquire/release cache-maintenance (buffer_inv/wbl2)
// anywhere in the loop. Ordering: stores drained by the s_waitcnt vmcnt(0)
// the compiler emits before __syncthreads, then tid0 bumps the flag.
__global__ __launch_bounds__(512, 2) void k_scan(
        const float* __restrict__ inputs, const float* __restrict__ wq,
        const float* __restrict__ w1g, const float* __restrict__ att_bq,
        const float* __restrict__ bp_b1, const float* __restrict__ bp_b2,
        const float* __restrict__ att_v,
        float* __restrict__ ws, float* __restrict__ attns) {
    __shared__ __align__(16) char smem[63488];
    int bid = blockIdx.x, tid = threadIdx.x;
    int* prog = (int*)(ws + OFF_FLG);        // prog[t*16]
    int* cons = prog + 1600;                 // cons[t*16]

    if (bid < NWORK) {
        // ================= WORKER =================
        int kc = bid / NCT, ct = bid % NCT;
        float* ulds = (float*)smem;
        float* red  = (float*)(smem + UKL*USTR*4);
        int cp = tid & 31, kq = (tid >> 5) & 7;
        bool comp = tid < 256;
        int g0 = ct*64 + cp, g1 = g0 + 32;
        float w0[KPT], w1r[KPT];
        #pragma unroll
        for (int g = 0; g < KPT; g++) { w0[g] = 0.f; w1r[g] = 0.f; }
        if (comp) {
            #pragma unroll
            for (int g = 0; g < KPT; g++) {
                int kl = kq*KPT + g;
                int kg = kc*WCH + kl;
                if (kl < WCH && kg < BS) {
                    int w = kg/336, d = kg - 336*w;
                    if (g0 < 256)      w0[g] = wq[((16-w)*336+d)*HID + g0];
                    else if (g0 < 827 && kg >= 336)
                                       w0[g] = w1g[((17-w)*336+d)*BH + (g0-256)];
                    if (g1 < 256)      w1r[g] = wq[((16-w)*336+d)*HID + g1];
                    else if (g1 < 827 && kg >= 336)
                                       w1r[g] = w1g[((17-w)*336+d)*BH + (g1-256)];
                }
            }
        }
        int khiv = kc*WCH + WCH - 1; if (khiv > BS-1) khiv = BS-1;
        int whi = khiv / 336;
        for (int t = 0; t < TDEC; t++) {
            int s = t + whi - 17; int s2 = t - 2;
            if (s2 > s) s = s2;
            if (tid == 0 && s >= 0) {
                while (__hip_atomic_load(&cons[s*16], RLX, AGT) < B)
                    __builtin_amdgcn_s_sleep(2);
            }
            __syncthreads();
            for (int e = tid; e < B*UKL; e += 512) {
                int b = e / UKL, kl = e - b*UKL;
                float v = 0.f;
                int kg = kc*WCH + kl;
                if (kl < WCH && kg < BS) {
                    int w = kg/336, d = kg - 336*w;
                    v = __hip_atomic_load(&ws[OFF_U + ((t + w)*B + b)*BD + d], RLX, AGT);
                }
                ulds[kl*USTR + b] = v;
            }
            __syncthreads();
            if (comp) {
                float a0[16], a1[16];
                #pragma unroll
                for (int i = 0; i < 16; i++) { a0[i] = 0.f; a1[i] = 0.f; }
                #pragma unroll
                for (int g = 0; g < KPT; g++) {
                    int kb = (kq*KPT + g)*USTR;
                    float uu[16];
                    *(float4*)&uu[0]  = *(const float4*)&ulds[kb];
                    *(float4*)&uu[4]  = *(const float4*)&ulds[kb+4];
                    *(float4*)&uu[8]  = *(const float4*)&ulds[kb+8];
                    *(float4*)&uu[12] = *(const float4*)&ulds[kb+12];
                    float wa = w0[g], wb = w1r[g];
                    #pragma unroll
                    for (int bb = 0; bb < 16; bb++) {
                        a0[bb] = fmaf(wa, uu[bb], a0[bb]);
                        a1[bb] = fmaf(wb, uu[bb], a1[bb]);
                    }
                }
                #pragma unroll
                for (int bb = 0; bb < 16; bb++) {
                    red[kq*1024 + bb*64 + cp]      = a0[bb];
                    red[kq*1024 + bb*64 + cp + 32] = a1[bb];
                }
            }
            __syncthreads();
            int par = t & 1;
            for (int oi = tid; oi < 1024; oi += 512) {
                float sacc = 0.f;
                #pragma unroll
                for (int q = 0; q < 8; q++) sacc += red[q*1024 + oi];
                int bb = oi >> 6, cl = oi & 63;
                __hip_atomic_store(
                    &ws[OFF_P + (((par*NWKC + kc)*B + bb)*832) + ct*64 + cl],
                    sacc, RLX, AGT);
            }
            __syncthreads();   // drains vmcnt(0) across all waves
            if (tid == 0)
                __hip_atomic_fetch_add(&prog[t*16], 1, RLX, AGT);
        }
    } else {
        // ================= CONSUMER =================
        int b = bid - NWORK;
        float* pqa    = (float*)smem;            // 832
        float* sc     = pqa + 832;               // 128
        float* attn_s = sc + 128;                // 128
        float* ctx2   = attn_s + 128;            // 512
        float* topv   = ctx2 + 512;              // 336  (16B aligned: off 1600)
        float* h1     = topv + 336;              // 572  (16B aligned: off 1936)
        float* avs    = h1 + 572;                // 256
        const float* w1T = ws + OFF_T1;
        const float* w2T = ws + OFF_T2;
        if (tid < 256) avs[tid] = att_v[tid];
        if (tid == 0) h1[571] = 0.f;             // pad for float4 u-loop
        for (int t = 0; t < TDEC; t++) {
            if (tid == 0) {
                while (__hip_atomic_load(&prog[t*16], RLX, AGT) < NWORK)
                    __builtin_amdgcn_s_sleep(2);
            }
            __syncthreads();
            int par = t & 1;
            for (int col = tid; col < 827; col += 512) {
                float ssum = 0.f;
                #pragma unroll
                for (int q = 0; q < NWKC; q++)
                    ssum += __hip_atomic_load(
                        &ws[OFF_P + (((par*NWKC + q)*B + b)*832) + col], RLX, AGT);
                pqa[col] = ssum + (col < HID ? att_bq[col] : bp_b1[col-HID]);
            }
            __syncthreads();
            {   // scores: thread = j*4 + hq
                int j = tid >> 2, hq = tid & 3;
                const float* par_ = ws + OFF_PA + (b*TENC + j)*HID + hq*64;
                const float* pqh = &pqa[hq*64];
                const float* avh = &avs[hq*64];
                float a = 0.f;
                #pragma unroll 8
                for (int h = 0; h < 64; h++) {
                    float x = pqh[h] + par_[h];
                    float e = __expf(2.f*x);
                    a += avh[h]*(1.f - 2.f/(e + 1.f));
                }
                a += __shfl_xor(a, 1);
                a += __shfl_xor(a, 2);
                if (hq == 0) sc[j] = a;
            }
            __syncthreads();
            if (tid < 64) {
                float s0 = sc[2*tid], s1 = sc[2*tid+1];
                float m = fmaxf(s0, s1);
                #pragma unroll
                for (int off = 1; off < 64; off <<= 1) m = fmaxf(m, __shfl_xor(m, off));
                float e0 = __expf(s0 - m), e1 = __expf(s1 - m);
                float ssum = e0 + e1;
                #pragma unroll
                for (int off = 1; off < 64; off <<= 1) ssum += __shfl_xor(ssum, off);
                float r = 1.f/ssum;
                attn_s[2*tid] = e0*r; attn_s[2*tid+1] = e1*r;
                attns[(b*TDEC + t)*TENC + 2*tid]   = e0*r;
                attns[(b*TDEC + t)*TENC + 2*tid+1] = e1*r;
            }
            __syncthreads();
            {   // ctx
                int i = tid & 255, jh = tid >> 8;
                const float* inp = inputs + (b*TENC + jh*64)*IND + i;
                float csum = 0.f;
                #pragma unroll 8
                for (int j = 0; j < 64; j++)
                    csum += attn_s[jh*64 + j]*inp[j*IND];
                ctx2[jh*256 + i] = csum;
            }
            __syncthreads();
            if (tid < 256) topv[tid] = ctx2[tid] + ctx2[256 + tid];
            else if (tid < BD) topv[tid] = ws[OFF_MEM + (t*B + b)*MD + (tid-256)];
            __syncthreads();
            for (int c = tid; c < BH; c += 512) {
                float v = pqa[HID + c];
                const float4* wp = (const float4*)&w1T[c*336];
                const float4* t4 = (const float4*)topv;
                #pragma unroll 4
                for (int q = 0; q < 84; q++) {
                    float4 w4 = wp[q], tt = t4[q];
                    v = fmaf(w4.x, tt.x, v); v = fmaf(w4.y, tt.y, v);
                    v = fmaf(w4.z, tt.z, v); v = fmaf(w4.w, tt.w, v);
                }
                h1[c] = fmaxf(v, 0.f);
            }
            __syncthreads();
            if (tid < BD) {
                float v = bp_b2[tid];
                const float4* wp = (const float4*)&w2T[tid*572];
                const float4* h4 = (const float4*)h1;
                #pragma unroll 4
                for (int q = 0; q < 143; q++) {
                    float4 w4 = wp[q], hh = h4[q];
                    v = fmaf(w4.x, hh.x, v); v = fmaf(w4.y, hh.y, v);
                    v = fmaf(w4.z, hh.z, v); v = fmaf(w4.w, hh.w, v);
                }
                __hip_atomic_store(&ws[OFF_U + ((t + 17)*B + b)*BD + tid], v, RLX, AGT);
            }
            __syncthreads();   // drains vmcnt(0)
            if (tid == 0)
                __hip_atomic_fetch_add(&cons[t*16], 1, RLX, AGT);
        }
    }
}

__global__ __launch_bounds__(256) void k_q2(float* __restrict__ ws) {
    int bid = blockIdx.x;
    int lc = bid & 3, tt = (bid >> 2) % 7, b = bid / 28;
    int l0 = lc*4, le = (lc == 3) ? 5 : 4;
    int t0 = tt*16;
    int ns = 15 + le;
    int s0 = t0 + 17 - (l0 + le - 1);
    __shared__ __align__(16) float Uw[20*336];
    int tid = threadIdx.x;
    for (int idx = tid; idx < ns*336; idx += 256) {
        int r = idx/336, d = idx - r*336;
        int slot = s0 + r;
        Uw[idx] = (slot >= 0 && slot < NSLOT) ? ws[OFF_U + (slot*B + b)*BD + d] : 0.f;
    }
    __syncthreads();
    int o0 = tid, o1 = tid + 256;
    bool v1 = o1 < OD;
    float a[16], c[16];
    #pragma unroll
    for (int i = 0; i < 16; i++) { a[i] = 0.f; c[i] = 0.f; }
    for (int l = l0; l < l0 + le; l++) {
        const float* Mrow = ws + OFF_M + l*BD*OD;
        const float* urow = &Uw[(l0 + le - 1 - l)*336];
        for (int dg = 0; dg < 84; dg++) {
            int d = dg*4;
            float m00 = Mrow[(d+0)*OD + o0], m01 = Mrow[(d+1)*OD + o0];
            float m02 = Mrow[(d+2)*OD + o0], m03 = Mrow[(d+3)*OD + o0];
            float m10 = 0.f, m11 = 0.f, m12 = 0.f, m13 = 0.f;
            if (v1) {
                m10 = Mrow[(d+0)*OD + o1]; m11 = Mrow[(d+1)*OD + o1];
                m12 = Mrow[(d+2)*OD + o1]; m13 = Mrow[(d+3)*OD + o1];
            }
            #pragma unroll
            for (int q = 0; q < 16; q++) {
                float4 u4 = *(const float4*)&urow[q*336 + d];
                a[q] = fmaf(u4.x, m00, a[q]); a[q] = fmaf(u4.y, m01, a[q]);
                a[q] = fmaf(u4.z, m02, a[q]); a[q] = fmaf(u4.w, m03, a[q]);
                c[q] = fmaf(u4.x, m10, c[q]); c[q] = fmaf(u4.y, m11, c[q]);
                c[q] = fmaf(u4.z, m12, c[q]); c[q] = fmaf(u4.w, m13, c[q]);
            }
        }
    }
    float* Q = ws + OFF_Q + (lc*B + b)*TDEC*OD;
    for (int q = 0; q < 16; q++) {
        int tp = t0 + q;
        if (tp < TDEC) {
            Q[tp*OD + o0] = a[q];
            if (v1) Q[tp*OD + o1] = c[q];
        }
    }
}

__global__ __launch_bounds__(256) void k_q3(float* __restrict__ outs,
        const float* __restrict__ ws) {
    int i = blockIdx.x*256 + threadIdx.x;
    if (i < B*TDEC*OD) {
        int o = i % OD;
        float v = ws[OFF_CO + o];
        #pragma unroll
        for (int lc = 0; lc < 4; lc++) v += ws[OFF_Q + lc*B*TDEC*OD + i];
        outs[i] = v;
    }
}

extern "C" void kernel_launch(void* const* d_in, const int* in_sizes, int n_in,
                              void* d_out, int out_size, void* d_ws, size_t ws_size,
                              hipStream_t stream) {
    const float* inputs  = (const float*)d_in[0];
    const float* targets = (const float*)d_in[1];
    const float* mp_w1   = (const float*)d_in[2];
    const float* mp_b1   = (const float*)d_in[3];
    const float* mp_w2   = (const float*)d_in[4];
    const float* mp_b2   = (const float*)d_in[5];
    const float* bp_w1   = (const float*)d_in[6];
    const float* bp_b1   = (const float*)d_in[7];
    const float* bp_w2   = (const float*)d_in[8];
    const float* bp_b2   = (const float*)d_in[9];
    const float* att_wq  = (const float*)d_in[10];
    const float* att_bq  = (const float*)d_in[11];
    const float* att_wa  = (const float*)d_in[12];
    const float* att_ba  = (const float*)d_in[13];
    const float* att_v   = (const float*)d_in[14];
    const float* scale_w = (const float*)d_in[15];
    const float* scale_b = (const float*)d_in[16];
    const float* out_w   = (const float*)d_in[17];
    const float* out_b   = (const float*)d_in[18];
    float* ws = (float*)d_ws;
    float* outs = (float*)d_out;
    float* attns = outs + B*TDEC*OD;

    k_init<<<372, 256, 0, stream>>>(ws);
    k_pa  <<<B*TENC, 256, 0, stream>>>(inputs, att_wa, att_ba, ws);
    k_mem <<<TDEC*B, 128, 0, stream>>>(targets, mp_w1, mp_b1, mp_w2, mp_b2, ws);
    k_M   <<<17*14, 256, 0, stream>>>(scale_w, out_w, ws);
    k_cout<<<17, 256, 0, stream>>>(scale_b, out_w, out_b, ws);
    k_tr  <<<1501, 256, 0, stream>>>(bp_w1, bp_w2, ws);
    k_scan<<<NBLK, 512, 0, stream>>>(inputs, att_wq, bp_w1, att_bq, bp_b1,
                                     bp_b2, att_v, ws, attns);
    k_q2  <<<16*7*4, 256, 0, stream>>>(ws);
    k_q3  <<<(B*TDEC*OD + 255)/256, 256, 0, stream>>>(outs, ws);
}